// Round 9
// baseline (156.887 us; speedup 1.0000x reference)
//
#include <hip/hip_runtime.h>

// ExplaiNN inference on MFMA (bf16 matrix cores, f32 accumulate). 4 kernels:
// prep_all:  conv_w -> Wc[kc][304][8] bf16; W1 -> W1b[g][kc][112][8] bf16 (B-frag layout);
//            x -> xg[b][phi*4+c][1056] bf16 phase-shifted fragment image (global, 8.65MB)
//            replacing per-block LDS staging; BN1 -> AB1[304] float2 (A1,B1).
// conv_mfma: r7 restructure, r9 INDEX FIX: 3584 single-wave blocks (b x 7 p-tiles x
//            2 d-halves), NO LDS / NO barrier / NO prologue. af from 15 coalesced xg
//            loads (L2), B-frags global-direct from Wc, BN via AB1. 14 waves/CU.
//            r8 bug: base0 had a spurious +9 (pad applied twice) -> conv read x
//            shifted by 9 taps, absmax 2.34. xg local coord == x_pad coord; fixed.
// mlp_mfma:  per-group GEMM + BN2/ReLU + W2-dot + BN3/ReLU -> h2ws[g][b]  (r5, unchanged).
//            Staging combines pool0/pool1 via u16 max (post-ReLU bf16 >= 0: monotone).
// classifier: h2 @ cls_w^T + cls_b -> out[256][2] f32  (unchanged).

typedef unsigned short ushort_t;
typedef short short8 __attribute__((ext_vector_type(8)));
typedef float floatx4 __attribute__((ext_vector_type(4)));

constexpr float EPSf = 1e-5f;

__device__ __forceinline__ ushort_t f2bf(float f) {
    unsigned u = __float_as_uint(f);
    unsigned r = (u + 0x7FFFu + ((u >> 16) & 1u)) >> 16;   // round-to-nearest-even
    return (ushort_t)r;
}

__device__ __forceinline__ unsigned maxu16x2(unsigned a, unsigned b) {
    unsigned lo = (a & 0xffffu) > (b & 0xffffu) ? (a & 0xffffu) : (b & 0xffffu);
    unsigned hi = (a >> 16) > (b >> 16) ? (a >> 16) : (b >> 16);
    return lo | (hi << 16);
}

// opaque def of a uint4, component-wise (hipcc rejects tied 128-bit asm operands)
__device__ __forceinline__ void pin4(uint4& v) {
    asm volatile("" : "+v"(v.x), "+v"(v.y), "+v"(v.z), "+v"(v.w));
}

// ---------------- prep: weight + input-image transforms ----------------
// xg row layout: xg[b][phi*4+c][i] = x[c][i + phi - 9] = x_pad[c][i + phi].
// => xg LOCAL coordinate equals the x_pad coordinate G: phi = G&3, bi = G-phi
// (8B-aligned), row-phi slots bi..bi+7 = x_pad[G..G+7]. Max G read = 1015 (+7 < 1056).
constexpr int WC_BLKS  = 114;    // 29,184 ushorts = 12*304*8
constexpr int W1B_BLKS = 4256;   // 8 xcd * 38 g * 14 blocks (3584 thr/g = 16kc*112h*2jj)
constexpr int XG_BLKS  = 8448;   // 256b * 16 rows * 528 uints / 256 thr
constexpr int XG_ROW   = 1056;   // elems per (phi,c) row
__global__ __launch_bounds__(256) void prep_all(
    const float* __restrict__ conv_w, const float* __restrict__ W1,
    const float* __restrict__ x,
    const float* __restrict__ conv_b, const float* __restrict__ g1,
    const float* __restrict__ be1, const float* __restrict__ m1, const float* __restrict__ v1,
    ushort_t* __restrict__ Wc, ushort_t* __restrict__ W1b,
    ushort_t* __restrict__ xg, float2* __restrict__ AB1)
{
    const int blk = blockIdx.x, t = threadIdx.x;
    if (blk < WC_BLKS) {
        int idx = blk * 256 + t;                     // exact: 114*256 = 29,184
        int j = idx & 7, g = (idx >> 3) % 304, kc = idx / (304 * 8);
        int k = kc * 8 + j, c = k / 24, tt = k - c * 24;
        float v = (g < 300 && tt < 19) ? conv_w[g * 76 + c * 19 + tt] : 0.f;
        Wc[idx] = f2bf(v);
    } else if (blk < WC_BLKS + W1B_BLKS) {
        // W1b[g][kc][h][8]; blk&7 selects XCD-local g range (38 g per XCD slice)
        int blk2 = blk - WC_BLKS;
        int xcd = blk2 & 7, j = blk2 >> 3;
        int gl = j / 14, inner = j - gl * 14;
        int g = xcd * 38 + gl;
        if (g >= 300) return;
        int v = inner * 256 + t;                     // 0..3583
        int jj = v & 1, r = v >> 1;
        int h = r % 112, kc = r / 112;
        int i0 = kc * 8 + jj * 4;
        ushort4 o = make_ushort4(0, 0, 0, 0);
        if (h < 100 && i0 <= 96) {
            float4 w = *(const float4*)&W1[(size_t)g * 10000 + h * 100 + i0];
            o = make_ushort4(f2bf(w.x), f2bf(w.y), f2bf(w.z), f2bf(w.w));
        }
        *(ushort4*)&W1b[((size_t)(g * 16 + kc) * 112 + h) * 8 + jj * 4] = o;
    } else if (blk < WC_BLKS + W1B_BLKS + XG_BLKS) {
        // xg: one packed uint (2 bf16) per thread; U = rr*528 + iu, rr = b*16 + phi*4 + c
        int U = (blk - WC_BLKS - W1B_BLKS) * 256 + t;
        int iu = U % 528, rr = U / 528;
        int c = rr & 3, phi = (rr >> 2) & 3, b = rr >> 4;
        int idx0 = 2 * iu + phi - 9;                 // x index of low element
        const float* xb = x + b * 4000 + c * 1000;
        float v0 = ((unsigned)idx0 < 1000u) ? xb[idx0] : 0.f;
        float v1_ = ((unsigned)(idx0 + 1) < 1000u) ? xb[idx0 + 1] : 0.f;
        ((unsigned*)xg)[U] = (unsigned)f2bf(v0) | ((unsigned)f2bf(v1_) << 16);
    } else {
        // AB1[304]: (A1, B1) BN1 affine pairs
        for (int i = t; i < 304; i += 256) {
            float A = 0.f, Bv = 0.f;
            if (i < 300) {
                A = g1[i] * rsqrtf(v1[i] + EPSf);
                Bv = (conv_b[i] - m1[i]) * A + be1[i];
            }
            AB1[i] = make_float2(A, Bv);
        }
    }
}

// ---------------- Stage 1: conv via MFMA, single-wave blocks, LDS-free ----------------
// grid (256, 14): b = blockIdx.x; z = blockIdx.y: dh = z&1 (d 0..4 / 5..9), tl = z>>1
// (p-tile 0..6, p0 = 16*tl, valid p <= 99). C[m=p][n=g]; max over the wave's d-half.
__global__ __launch_bounds__(64, 4) void conv_mfma(
    const ushort_t* __restrict__ xg, const ushort_t* __restrict__ Wc,
    const float2* __restrict__ AB1,
    ushort_t* __restrict__ pool0, ushort_t* __restrict__ pool1)
{
    const int lane = threadIdx.x;
    const int b = blockIdx.x, z = blockIdx.y;
    const int dh = z & 1, tl = z >> 1;

    // zero the 256B pad after EACH partial buffer (mlp overreads <=54B past last row;
    // ws is NaN-poisoned and NaN*0 = NaN through the zero-weight MFMA lanes).
    if (b == 0 && z == 0 && lane < 32) {
        ushort_t* bufp = (lane & 16) ? pool1 : pool0;
        uint4 zz = {0, 0, 0, 0};
        *(uint4*)&bufp[7680000 + (lane & 15) * 8] = zz;
    }

    const int row = lane & 15, quad = lane >> 4;
    const int p0 = tl * 16;
    const int p_r = p0 + row;
    const int prc = (p_r < 99) ? p_r : 99;      // clamp keeps xg reads in range (rows masked at store)
    ushort_t* __restrict__ dstbuf = dh ? pool1 : pool0;
    const ushort_t* __restrict__ xgb = xg + (size_t)b * (16 * XG_ROW);

    // A fragments for this wave's 5 d-shifts: 15 x uint4 = 60 VGPR (coalesced L2 loads).
    uint4 af[5][3];
#pragma unroll
    for (int s = 0; s < 3; ++s) {
        int k0 = s * 32 + quad * 8;
        int c = k0 / 24, t0 = k0 - c * 24;
        int base0 = 10 * prc + t0 + dh * 5;      // x_pad coord of dd=0 (r8 bug: had +9; max 1015)
#pragma unroll
        for (int dd = 0; dd < 5; ++dd) {
            int local = base0 + dd;
            int phi = local & 3, bi = local - phi;
            const ushort_t* p = &xgb[(phi * 4 + c) * XG_ROW + bi];  // 8B-aligned
            uint2 lo = *(const uint2*)p;
            uint2 hi = *(const uint2*)(p + 4);
            af[dd][s] = (uint4){lo.x, lo.y, hi.x, hi.y};
        }
    }
#pragma unroll
    for (int dd = 0; dd < 5; ++dd)
#pragma unroll
        for (int s = 0; s < 3; ++s)
            pin4(af[dd][s]);

    // per-lane B-frag base pointers into global Wc (L2-resident; 16B/lane, 16B-aligned)
    const ushort_t* wb0 = Wc + ((size_t)((0 * 4 + quad) * 304) + row) * 8;
    const ushort_t* wb1 = Wc + ((size_t)((1 * 4 + quad) * 304) + row) * 8;
    const ushort_t* wb2 = Wc + ((size_t)((2 * 4 + quad) * 304) + row) * 8;

    for (int gt = 0; gt < 19; ++gt) {
        short8 bf[3];
        {   // 16 g-rows * 8 ushorts = 256 B stride per gt step
            uint4 t0 = *(const uint4*)(wb0 + (size_t)gt * 128);
            uint4 t1 = *(const uint4*)(wb1 + (size_t)gt * 128);
            uint4 t2 = *(const uint4*)(wb2 + (size_t)gt * 128);
            bf[0] = __builtin_bit_cast(short8, t0);
            bf[1] = __builtin_bit_cast(short8, t1);
            bf[2] = __builtin_bit_cast(short8, t2);
        }
        const float2 ab = AB1[gt * 16 + row];
        const float a1v = ab.x, b1v = ab.y;
        floatx4 mx = {0.f, 0.f, 0.f, 0.f};     // ReLU floor (valid per-half: both halves >= 0)
#pragma unroll
        for (int dd = 0; dd < 5; ++dd) {
            floatx4 acc = {0.f, 0.f, 0.f, 0.f};
#pragma unroll
            for (int s = 0; s < 3; ++s)
                acc = __builtin_amdgcn_mfma_f32_16x16x32_bf16(
                    __builtin_bit_cast(short8, af[dd][s]), bf[s], acc, 0, 0, 0);
#pragma unroll
            for (int r = 0; r < 4; ++r)
                mx[r] = fmaxf(mx[r], fmaf(acc[r], a1v, b1v));
        }
        const int g = gt * 16 + row;            // C col = lane&15
        const int pr0 = p0 + quad * 4;          // C rows = quad*4 + r
        if (g < 300 && pr0 + 3 <= 99) {
            ushort4 o = make_ushort4(f2bf(mx[0]), f2bf(mx[1]), f2bf(mx[2]), f2bf(mx[3]));
            *(ushort4*)&dstbuf[((size_t)b * 300 + g) * 100 + pr0] = o;
        }
    }
}

// ---------------- Stage 2: grouped MLP via MFMA (r5, unchanged) ----------------
// grid 608: blk&7 = XCD slice, 38 g each, 2 b-halves per g on the same slice.
__global__ __launch_bounds__(256, 2) void mlp_mfma(
    const ushort_t* __restrict__ pool0, const ushort_t* __restrict__ pool1,
    const ushort_t* __restrict__ W1b,
    const float* __restrict__ b1, const float* __restrict__ g2, const float* __restrict__ be2,
    const float* __restrict__ m2, const float* __restrict__ v2,
    const float* __restrict__ W2, const float* __restrict__ b2,
    const float* __restrict__ g3, const float* __restrict__ be3,
    const float* __restrict__ m3, const float* __restrict__ v3,
    float* __restrict__ h2ws)
{
    __shared__ ushort_t W1l[16 * 112 * 8];     // 28672 B, [kc][h][8]
    __shared__ ushort_t pl[128 * 128];         // 32768 B, [bl][chunk^(bl&7)][8]
    __shared__ float A2s[112], C2s[112], w2sl[112];
    __shared__ float sA3, sC3;

    const int tid = threadIdx.x;
    const int blk = blockIdx.x;
    const int xcd = blk & 7, j = blk >> 3;
    const int g = xcd * 38 + (j >> 1);
    if (g >= 300) return;
    const int b0 = (j & 1) * 128;

    {   // pure linear copy of prepped B-frag image (conflict-free)
        const uint4* src = (const uint4*)(W1b + (size_t)g * 14336);
        uint4* dst = (uint4*)W1l;
        for (int i = tid; i < 1792; i += 256) dst[i] = src[i];
    }
    for (int qq = tid; qq < 128 * 16; qq += 256) {
        int bl = qq >> 4, kc = qq & 15;
        size_t off = ((size_t)(b0 + bl) * 300 + g) * 100 + kc * 8;
        const ushort_t* sA = pool0 + off;       // rows 200B apart: 8B-aligned
        const ushort_t* sB = pool1 + off;       // i>=100 spills into next row / zero pad (finite)
        uint2 loA = *(const uint2*)sA, hiA = *(const uint2*)(sA + 4);
        uint2 loB = *(const uint2*)sB, hiB = *(const uint2*)(sB + 4);
        uint4 m;                                // combine d-halves: u16 max (post-ReLU bf16 >= 0)
        m.x = maxu16x2(loA.x, loB.x);
        m.y = maxu16x2(loA.y, loB.y);
        m.z = maxu16x2(hiA.x, hiB.x);
        m.w = maxu16x2(hiA.y, hiB.y);
        int swz = kc ^ (bl & 7);
        *(uint4*)&pl[((bl * 16) + swz) * 8] = m;
    }
    if (tid < 112) {
        float a2 = 0.f, c2 = 0.f, w2v = 0.f;
        if (tid < 100) {
            int qq = g * 100 + tid;
            a2 = g2[qq] * rsqrtf(v2[qq] + EPSf);
            c2 = (b1[qq] - m2[qq]) * a2 + be2[qq];
            w2v = W2[qq];
        }
        A2s[tid] = a2; C2s[tid] = c2; w2sl[tid] = w2v;
    }
    if (tid == 0) {
        float a3 = g3[g] * rsqrtf(v3[g] + EPSf);
        sA3 = a3; sC3 = (b2[g] - m3[g]) * a3 + be3[g];
    }
    __syncthreads();

    const int w = tid >> 6, lane = tid & 63;
    const int col = lane & 15, quad = lane >> 4;

    uint4 bfr[7][4];                           // all B-frags cached (112 VGPR), pinned below
#pragma unroll
    for (int nt = 0; nt < 7; ++nt)
#pragma unroll
        for (int s = 0; s < 4; ++s)
            bfr[nt][s] = *(const uint4*)&W1l[(((s * 4 + quad) * 112) + nt * 16 + col) * 8];
#pragma unroll
    for (int nt = 0; nt < 7; ++nt)
#pragma unroll
        for (int s = 0; s < 4; ++s)
            pin4(bfr[nt][s]);

#pragma unroll
    for (int mi = 0; mi < 2; ++mi) {
        const int mt = w * 2 + mi;
        const int bl = mt * 16 + col;          // A row
        uint4 afr[4];
#pragma unroll
        for (int s = 0; s < 4; ++s) {
            int kc = s * 4 + quad;
            afr[s] = *(const uint4*)&pl[((bl * 16) + (kc ^ (bl & 7))) * 8];
        }
        float run0 = 0.f, run1 = 0.f, run2 = 0.f, run3 = 0.f;
#pragma unroll
        for (int nt = 0; nt < 7; ++nt) {
            floatx4 acc = {0.f, 0.f, 0.f, 0.f};
#pragma unroll
            for (int s = 0; s < 4; ++s)
                acc = __builtin_amdgcn_mfma_f32_16x16x32_bf16(
                    __builtin_bit_cast(short8, afr[s]), __builtin_bit_cast(short8, bfr[nt][s]), acc, 0, 0, 0);
            const float a2v = A2s[nt * 16 + col], c2v = C2s[nt * 16 + col], w2v = w2sl[nt * 16 + col];
            run0 += fmaxf(fmaf(acc[0], a2v, c2v), 0.f) * w2v;
            run1 += fmaxf(fmaf(acc[1], a2v, c2v), 0.f) * w2v;
            run2 += fmaxf(fmaf(acc[2], a2v, c2v), 0.f) * w2v;
            run3 += fmaxf(fmaf(acc[3], a2v, c2v), 0.f) * w2v;
        }
#pragma unroll
        for (int m = 1; m <= 8; m <<= 1) {     // sum over the 16 h-cols
            run0 += __shfl_xor(run0, m, 64);
            run1 += __shfl_xor(run1, m, 64);
            run2 += __shfl_xor(run2, m, 64);
            run3 += __shfl_xor(run3, m, 64);
        }
        if (col == 0) {
            float4 o;
            o.x = fmaxf(fmaf(run0, sA3, sC3), 0.f);
            o.y = fmaxf(fmaf(run1, sA3, sC3), 0.f);
            o.z = fmaxf(fmaf(run2, sA3, sC3), 0.f);
            o.w = fmaxf(fmaf(run3, sA3, sC3), 0.f);
            *(float4*)&h2ws[g * 256 + b0 + mt * 16 + quad * 4] = o;
        }
    }
}

// ---------------- Stage 3: classifier ----------------
__global__ __launch_bounds__(64) void classifier_kernel(
    const float* __restrict__ h2ws, const float* __restrict__ cls_w,
    const float* __restrict__ cls_b, float* __restrict__ out) {
    const int b = blockIdx.x, t = threadIdx.x;
    float a0 = 0.f, a1 = 0.f;
    for (int gg = t; gg < 300; gg += 64) {
        float v = h2ws[gg * 256 + b];
        a0 = fmaf(v, cls_w[gg], a0);
        a1 = fmaf(v, cls_w[300 + gg], a1);
    }
#pragma unroll
    for (int off = 32; off; off >>= 1) {
        a0 += __shfl_down(a0, off);
        a1 += __shfl_down(a1, off);
    }
    if (t == 0) {
        out[b * 2 + 0] = a0 + cls_b[0];
        out[b * 2 + 1] = a1 + cls_b[1];
    }
}

extern "C" void kernel_launch(void* const* d_in, const int* in_sizes, int n_in,
                              void* d_out, int out_size, void* d_ws, size_t ws_size,
                              hipStream_t stream) {
    const float* x      = (const float*)d_in[0];
    const float* conv_w = (const float*)d_in[1];
    const float* conv_b = (const float*)d_in[2];
    const float* bn1_g  = (const float*)d_in[3];
    const float* bn1_b  = (const float*)d_in[4];
    const float* bn1_m  = (const float*)d_in[5];
    const float* bn1_v  = (const float*)d_in[6];
    const float* W1     = (const float*)d_in[7];
    const float* b1     = (const float*)d_in[8];
    const float* bn2_g  = (const float*)d_in[9];
    const float* bn2_b  = (const float*)d_in[10];
    const float* bn2_m  = (const float*)d_in[11];
    const float* bn2_v  = (const float*)d_in[12];
    const float* W2     = (const float*)d_in[13];
    const float* b2     = (const float*)d_in[14];
    const float* bn3_g  = (const float*)d_in[15];
    const float* bn3_b  = (const float*)d_in[16];
    const float* bn3_m  = (const float*)d_in[17];
    const float* bn3_v  = (const float*)d_in[18];
    const float* cls_w  = (const float*)d_in[19];
    const float* cls_b  = (const float*)d_in[20];

    char* wsb = (char*)d_ws;
    ushort_t* pool0 = (ushort_t*)(wsb);                  // 15,360,000 B + 256 B pad
    ushort_t* pool1 = (ushort_t*)(wsb + 15360512);       // 15,360,000 B + 256 B pad
    ushort_t* Wc    = (ushort_t*)(wsb + 30721024);       //     58,368 B
    ushort_t* W1b   = (ushort_t*)(wsb + 30779392);       //  8,601,600 B
    float*    h2ws  = (float*)  (wsb + 39380992);        //    307,200 B
    ushort_t* xg    = (ushort_t*)(wsb + 39688192);       //  8,650,752 B
    float2*   AB1   = (float2*) (wsb + 48338944);        //      2,432 B

    prep_all<<<dim3(WC_BLKS + W1B_BLKS + XG_BLKS + 1), 256, 0, stream>>>(
        conv_w, W1, x, conv_b, bn1_g, bn1_b, bn1_m, bn1_v, Wc, W1b, xg, AB1);

    conv_mfma<<<dim3(256, 14), 64, 0, stream>>>(xg, Wc, AB1, pool0, pool1);

    mlp_mfma<<<dim3(608), 256, 0, stream>>>(
        pool0, pool1, W1b, b1, bn2_g, bn2_b, bn2_m, bn2_v, W2, b2,
        bn3_g, bn3_b, bn3_m, bn3_v, h2ws);

    classifier_kernel<<<dim3(256), 64, 0, stream>>>(h2ws, cls_w, cls_b, (float*)d_out);
}

// Round 10
// 141.489 us; speedup vs baseline: 1.1088x; 1.1088x over previous
//
#include <hip/hip_runtime.h>

// ExplaiNN inference on MFMA (bf16 matrix cores, f32 accumulate). 4 kernels:
// prep_all:  conv_w -> Wc[kc][304][8] bf16; W1 -> W1b[g][kc][112][8] bf16 (B-frag layout).
// conv_mfma: implicit-GEMM conv + BN1 + ReLU + partial maxpool -> pool0/pool1 bf16.
//            d-SPLIT: 512 thr / 8 waves; wave w owns tile (w&3), d-half (w>>2); af[5][3]
//            pinned (60 VGPR). r10: gt-loop SOFTWARE-PIPELINED (double-buffered B-frags,
//            load gt+1 under gt's MFMAs — loop was never unrolled; serial {read, wait,
//            MFMA, VALU-chain, store} per gt was the surviving stall theory) + RAW-MAX
//            epilogue (max acc over dd BEFORE BN: A1=g1*rsqrt(v1+eps)>0 since g1,v1 in
//            [0.5,1.5] => BN monotone => commutes with max; ~40% less epilogue VALU).
// mlp_mfma:  per-group GEMM + BN2/ReLU + W2-dot + BN3/ReLU -> h2ws[g][b]  (r5, unchanged;
//            at its ~39MB memory floor). Combines pool0/pool1 via u16 max (values >= 0).
// classifier: h2 @ cls_w^T + cls_b -> out[256][2] f32  (unchanged).
// Ledger (r9 analysis): harness fixed overhead ~105-110us (1x 268MB fill @44 + ~22 tiny
// reset dispatches + gaps); controllable: conv ~25, mlp ~6, prep 3.5, cls 2.5.

typedef unsigned short ushort_t;
typedef short short8 __attribute__((ext_vector_type(8)));
typedef float floatx4 __attribute__((ext_vector_type(4)));

constexpr float EPSf = 1e-5f;

__device__ __forceinline__ ushort_t f2bf(float f) {
    unsigned u = __float_as_uint(f);
    unsigned r = (u + 0x7FFFu + ((u >> 16) & 1u)) >> 16;   // round-to-nearest-even
    return (ushort_t)r;
}

__device__ __forceinline__ unsigned maxu16x2(unsigned a, unsigned b) {
    unsigned lo = (a & 0xffffu) > (b & 0xffffu) ? (a & 0xffffu) : (b & 0xffffu);
    unsigned hi = (a >> 16) > (b >> 16) ? (a >> 16) : (b >> 16);
    return lo | (hi << 16);
}

// opaque def of a uint4, component-wise (hipcc rejects tied 128-bit asm operands)
__device__ __forceinline__ void pin4(uint4& v) {
    asm volatile("" : "+v"(v.x), "+v"(v.y), "+v"(v.z), "+v"(v.w));
}

// ---------------- prep: weight transforms ----------------
constexpr int WC_BLKS  = 114;    // 29,184 ushorts = 12*304*8
constexpr int W1B_BLKS = 4256;   // 8 xcd * 38 g * 14 blocks (3584 thr/g = 16kc*112h*2jj)
__global__ __launch_bounds__(256) void prep_all(
    const float* __restrict__ conv_w, const float* __restrict__ W1,
    ushort_t* __restrict__ Wc, ushort_t* __restrict__ W1b)
{
    const int blk = blockIdx.x, t = threadIdx.x;
    if (blk < WC_BLKS) {
        int idx = blk * 256 + t;                     // exact: 114*256 = 29,184
        int j = idx & 7, g = (idx >> 3) % 304, kc = idx / (304 * 8);
        int k = kc * 8 + j, c = k / 24, tt = k - c * 24;
        float v = (g < 300 && tt < 19) ? conv_w[g * 76 + c * 19 + tt] : 0.f;
        Wc[idx] = f2bf(v);
    } else {
        // W1b[g][kc][h][8]; blk&7 selects XCD-local g range (38 g per XCD slice)
        int blk2 = blk - WC_BLKS;
        int xcd = blk2 & 7, j = blk2 >> 3;
        int gl = j / 14, inner = j - gl * 14;
        int g = xcd * 38 + gl;
        if (g >= 300) return;
        int v = inner * 256 + t;                     // 0..3583
        int jj = v & 1, r = v >> 1;
        int h = r % 112, kc = r / 112;
        int i0 = kc * 8 + jj * 4;
        ushort4 o = make_ushort4(0, 0, 0, 0);
        if (h < 100 && i0 <= 96) {
            float4 w = *(const float4*)&W1[(size_t)g * 10000 + h * 100 + i0];
            o = make_ushort4(f2bf(w.x), f2bf(w.y), f2bf(w.z), f2bf(w.w));
        }
        *(ushort4*)&W1b[((size_t)(g * 16 + kc) * 112 + h) * 8 + jj * 4] = o;
    }
}

// ---------------- Stage 1: conv via MFMA, d-split, pipelined gt loop ----------------
// Window q=0: p 0..51 (4 M-tiles), q=1: p 52..99 (3 M-tiles). X0 = x_pad origin of LDS window.
// C[m=p][n=g] = sum_k A[m][k] B[k][n]; A[m][(c,t)] = x_pad[c][10(p)+d+t]; max over d in half.
__global__ __launch_bounds__(512, 4) void conv_mfma(
    const float* __restrict__ x, const ushort_t* __restrict__ Wc,
    const float* __restrict__ conv_b, const float* __restrict__ g1, const float* __restrict__ be1,
    const float* __restrict__ m1, const float* __restrict__ v1,
    ushort_t* __restrict__ pool0, ushort_t* __restrict__ pool1)
{
    __shared__ ushort_t Wl[12 * 304 * 8];      // 58368 B, [kc][g][8]
    __shared__ ushort_t xl[16 * 552];          // 17664 B, [(phi*4+c)][552], phase-shifted copies
    __shared__ float A1s[304], B1s[304];       // total 78464 B -> 2 blocks/CU (16 waves/CU)

    const int tid = threadIdx.x;
    const int b = blockIdx.x, q = blockIdx.y;
    const int X0 = q * 520;                     // x_pad coordinate of xl[.][0]

    // zero the 256B pad after EACH partial buffer (mlp overreads <=54B past last row;
    // ws is NaN-poisoned and NaN*0 = NaN through the zero-weight MFMA lanes).
    if (b == 0 && q == 0 && tid < 32) {
        ushort_t* bufp = (tid & 16) ? pool1 : pool0;
        uint4 z = {0, 0, 0, 0};
        *(uint4*)&bufp[7680000 + (tid & 15) * 8] = z;
    }

    // stage x (f32 global) -> 4 phase copies bf16 in LDS; copy phi elem i = x_pad[X0+i+phi]
    for (int u = tid; u < 16 * 276; u += 512) { // uint = 2 bf16
        int iu = u % 276, r = u / 276;
        int c = r & 3, phi = r >> 2;
        int gi = X0 + 2 * iu + phi - 9;         // x index of low element
        const float* xb = x + b * 4000 + c * 1000;
        float v0 = ((unsigned)gi < 1000u) ? xb[gi] : 0.f;
        float v1_ = ((unsigned)(gi + 1) < 1000u) ? xb[gi + 1] : 0.f;
        ((unsigned*)xl)[u] = (unsigned)f2bf(v0) | ((unsigned)f2bf(v1_) << 16);
    }
    {   // weights: linear 16B copy of prepped Wc (L2-resident, conflict-free)
        const uint4* wsrc = (const uint4*)Wc;
        uint4* wdst = (uint4*)Wl;
        for (int i = tid; i < 3648; i += 512) wdst[i] = wsrc[i];
    }
    for (int i = tid; i < 304; i += 512) {
        if (i < 300) {
            float A = g1[i] * rsqrtf(v1[i] + EPSf);
            A1s[i] = A;
            B1s[i] = (conv_b[i] - m1[i]) * A + be1[i];
        } else { A1s[i] = 0.f; B1s[i] = 0.f; }
    }
    __syncthreads();

    const int w = tid >> 6, lane = tid & 63;
    const int tile = w & 3, dh = w >> 2;        // dh=0: d 0..4, dh=1: d 5..9
    if (q == 1 && tile == 3) return;            // 3 tiles in window 1; no barriers after this
    const int p0 = q ? (52 + tile * 16) : (tile * 16);
    const int pmax = q ? 99 : 51;
    const int row = lane & 15, quad = lane >> 4;
    const int p_r = p0 + row;
    const int prc = (p_r < pmax) ? p_r : pmax;  // clamp keeps LDS reads in window (rows masked at store)
    ushort_t* __restrict__ dstbuf = dh ? pool1 : pool0;

    // A fragments for this wave's 5 d-shifts: 15 x uint4 = 60 VGPR.
    uint4 af[5][3];
#pragma unroll
    for (int s = 0; s < 3; ++s) {
        int k0 = s * 32 + quad * 8;
        int c = k0 / 24, t0 = k0 - c * 24;
        int base0 = 10 * prc + t0 - X0 + dh * 5; // local window coords, max 535 (q0) / 495 (q1)
#pragma unroll
        for (int dd = 0; dd < 5; ++dd) {
            int local = base0 + dd;
            int phi = local & 3, bi = local - phi;
            const ushort_t* p = &xl[(phi * 4 + c) * 552 + bi];  // 8B-aligned
            uint2 lo = *(const uint2*)p;
            uint2 hi = *(const uint2*)(p + 4);
            af[dd][s] = (uint4){lo.x, lo.y, hi.x, hi.y};
        }
    }
    // PIN: opaque volatile def per fragment — keep af register-resident across gt loop.
#pragma unroll
    for (int dd = 0; dd < 5; ++dd)
#pragma unroll
        for (int s = 0; s < 3; ++s)
            pin4(af[dd][s]);

    // --- pipelined gt loop: double-buffered B-frags, raw-max epilogue ---
    auto loadB = [&](short8* bf, int gt) {
#pragma unroll
        for (int s = 0; s < 3; ++s) {
            uint4 t4 = *(const uint4*)&Wl[(((s * 4 + quad) * 304) + gt * 16 + row) * 8];
            bf[s] = __builtin_bit_cast(short8, t4);
        }
    };
    auto compute = [&](const short8* bf, int gt) {
        floatx4 mx;
        {   // dd = 0 initializes the raw max
            floatx4 acc = {0.f, 0.f, 0.f, 0.f};
#pragma unroll
            for (int s = 0; s < 3; ++s)
                acc = __builtin_amdgcn_mfma_f32_16x16x32_bf16(
                    __builtin_bit_cast(short8, af[0][s]), bf[s], acc, 0, 0, 0);
            mx = acc;
        }
#pragma unroll
        for (int dd = 1; dd < 5; ++dd) {
            floatx4 acc = {0.f, 0.f, 0.f, 0.f};
#pragma unroll
            for (int s = 0; s < 3; ++s)
                acc = __builtin_amdgcn_mfma_f32_16x16x32_bf16(
                    __builtin_bit_cast(short8, af[dd][s]), bf[s], acc, 0, 0, 0);
#pragma unroll
            for (int r = 0; r < 4; ++r)
                mx[r] = fmaxf(mx[r], acc[r]);
        }
        const int g = gt * 16 + row;            // C col = lane&15
        const int pr0 = p0 + quad * 4;          // C rows = quad*4 + r
        if (g < 300 && pr0 + 3 <= pmax) {
            const float a1v = A1s[g], b1v = B1s[g];   // BN AFTER max (A1 > 0: monotone)
            ushort4 o;
            o.x = f2bf(fmaxf(fmaf(mx[0], a1v, b1v), 0.f));
            o.y = f2bf(fmaxf(fmaf(mx[1], a1v, b1v), 0.f));
            o.z = f2bf(fmaxf(fmaf(mx[2], a1v, b1v), 0.f));
            o.w = f2bf(fmaxf(fmaf(mx[3], a1v, b1v), 0.f));
            *(ushort4*)&dstbuf[((size_t)b * 300 + g) * 100 + pr0] = o;
        }
    };

    short8 bf0[3], bf1[3];
    loadB(bf0, 0);
    for (int gt = 0; gt < 19; gt += 2) {
        if (gt + 1 < 19) loadB(bf1, gt + 1);    // prefetch under gt's MFMAs
        compute(bf0, gt);
        if (gt + 2 < 19) loadB(bf0, gt + 2);    // prefetch under gt+1's MFMAs
        if (gt + 1 < 19) compute(bf1, gt + 1);
    }
}

// ---------------- Stage 2: grouped MLP via MFMA (r5, unchanged) ----------------
// grid 608: blk&7 = XCD slice, 38 g each, 2 b-halves per g on the same slice.
__global__ __launch_bounds__(256, 2) void mlp_mfma(
    const ushort_t* __restrict__ pool0, const ushort_t* __restrict__ pool1,
    const ushort_t* __restrict__ W1b,
    const float* __restrict__ b1, const float* __restrict__ g2, const float* __restrict__ be2,
    const float* __restrict__ m2, const float* __restrict__ v2,
    const float* __restrict__ W2, const float* __restrict__ b2,
    const float* __restrict__ g3, const float* __restrict__ be3,
    const float* __restrict__ m3, const float* __restrict__ v3,
    float* __restrict__ h2ws)
{
    __shared__ ushort_t W1l[16 * 112 * 8];     // 28672 B, [kc][h][8]
    __shared__ ushort_t pl[128 * 128];         // 32768 B, [bl][chunk^(bl&7)][8]
    __shared__ float A2s[112], C2s[112], w2sl[112];
    __shared__ float sA3, sC3;

    const int tid = threadIdx.x;
    const int blk = blockIdx.x;
    const int xcd = blk & 7, j = blk >> 3;
    const int g = xcd * 38 + (j >> 1);
    if (g >= 300) return;
    const int b0 = (j & 1) * 128;

    {   // pure linear copy of prepped B-frag image (conflict-free)
        const uint4* src = (const uint4*)(W1b + (size_t)g * 14336);
        uint4* dst = (uint4*)W1l;
        for (int i = tid; i < 1792; i += 256) dst[i] = src[i];
    }
    for (int qq = tid; qq < 128 * 16; qq += 256) {
        int bl = qq >> 4, kc = qq & 15;
        size_t off = ((size_t)(b0 + bl) * 300 + g) * 100 + kc * 8;
        const ushort_t* sA = pool0 + off;       // rows 200B apart: 8B-aligned
        const ushort_t* sB = pool1 + off;       // i>=100 spills into next row / zero pad (finite)
        uint2 loA = *(const uint2*)sA, hiA = *(const uint2*)(sA + 4);
        uint2 loB = *(const uint2*)sB, hiB = *(const uint2*)(sB + 4);
        uint4 m;                                // combine d-halves: u16 max (post-ReLU bf16 >= 0)
        m.x = maxu16x2(loA.x, loB.x);
        m.y = maxu16x2(loA.y, loB.y);
        m.z = maxu16x2(hiA.x, hiB.x);
        m.w = maxu16x2(hiA.y, hiB.y);
        int swz = kc ^ (bl & 7);
        *(uint4*)&pl[((bl * 16) + swz) * 8] = m;
    }
    if (tid < 112) {
        float a2 = 0.f, c2 = 0.f, w2v = 0.f;
        if (tid < 100) {
            int qq = g * 100 + tid;
            a2 = g2[qq] * rsqrtf(v2[qq] + EPSf);
            c2 = (b1[qq] - m2[qq]) * a2 + be2[qq];
            w2v = W2[qq];
        }
        A2s[tid] = a2; C2s[tid] = c2; w2sl[tid] = w2v;
    }
    if (tid == 0) {
        float a3 = g3[g] * rsqrtf(v3[g] + EPSf);
        sA3 = a3; sC3 = (b2[g] - m3[g]) * a3 + be3[g];
    }
    __syncthreads();

    const int w = tid >> 6, lane = tid & 63;
    const int col = lane & 15, quad = lane >> 4;

    uint4 bfr[7][4];                           // all B-frags cached (112 VGPR), pinned below
#pragma unroll
    for (int nt = 0; nt < 7; ++nt)
#pragma unroll
        for (int s = 0; s < 4; ++s)
            bfr[nt][s] = *(const uint4*)&W1l[(((s * 4 + quad) * 112) + nt * 16 + col) * 8];
#pragma unroll
    for (int nt = 0; nt < 7; ++nt)
#pragma unroll
        for (int s = 0; s < 4; ++s)
            pin4(bfr[nt][s]);

#pragma unroll
    for (int mi = 0; mi < 2; ++mi) {
        const int mt = w * 2 + mi;
        const int bl = mt * 16 + col;          // A row
        uint4 afr[4];
#pragma unroll
        for (int s = 0; s < 4; ++s) {
            int kc = s * 4 + quad;
            afr[s] = *(const uint4*)&pl[((bl * 16) + (kc ^ (bl & 7))) * 8];
        }
        float run0 = 0.f, run1 = 0.f, run2 = 0.f, run3 = 0.f;
#pragma unroll
        for (int nt = 0; nt < 7; ++nt) {
            floatx4 acc = {0.f, 0.f, 0.f, 0.f};
#pragma unroll
            for (int s = 0; s < 4; ++s)
                acc = __builtin_amdgcn_mfma_f32_16x16x32_bf16(
                    __builtin_bit_cast(short8, afr[s]), __builtin_bit_cast(short8, bfr[nt][s]), acc, 0, 0, 0);
            const float a2v = A2s[nt * 16 + col], c2v = C2s[nt * 16 + col], w2v = w2sl[nt * 16 + col];
            run0 += fmaxf(fmaf(acc[0], a2v, c2v), 0.f) * w2v;
            run1 += fmaxf(fmaf(acc[1], a2v, c2v), 0.f) * w2v;
            run2 += fmaxf(fmaf(acc[2], a2v, c2v), 0.f) * w2v;
            run3 += fmaxf(fmaf(acc[3], a2v, c2v), 0.f) * w2v;
        }
#pragma unroll
        for (int m = 1; m <= 8; m <<= 1) {     // sum over the 16 h-cols
            run0 += __shfl_xor(run0, m, 64);
            run1 += __shfl_xor(run1, m, 64);
            run2 += __shfl_xor(run2, m, 64);
            run3 += __shfl_xor(run3, m, 64);
        }
        if (col == 0) {
            float4 o;
            o.x = fmaxf(fmaf(run0, sA3, sC3), 0.f);
            o.y = fmaxf(fmaf(run1, sA3, sC3), 0.f);
            o.z = fmaxf(fmaf(run2, sA3, sC3), 0.f);
            o.w = fmaxf(fmaf(run3, sA3, sC3), 0.f);
            *(float4*)&h2ws[g * 256 + b0 + mt * 16 + quad * 4] = o;
        }
    }
}

// ---------------- Stage 3: classifier ----------------
__global__ __launch_bounds__(64) void classifier_kernel(
    const float* __restrict__ h2ws, const float* __restrict__ cls_w,
    const float* __restrict__ cls_b, float* __restrict__ out) {
    const int b = blockIdx.x, t = threadIdx.x;
    float a0 = 0.f, a1 = 0.f;
    for (int gg = t; gg < 300; gg += 64) {
        float v = h2ws[gg * 256 + b];
        a0 = fmaf(v, cls_w[gg], a0);
        a1 = fmaf(v, cls_w[300 + gg], a1);
    }
#pragma unroll
    for (int off = 32; off; off >>= 1) {
        a0 += __shfl_down(a0, off);
        a1 += __shfl_down(a1, off);
    }
    if (t == 0) {
        out[b * 2 + 0] = a0 + cls_b[0];
        out[b * 2 + 1] = a1 + cls_b[1];
    }
}

extern "C" void kernel_launch(void* const* d_in, const int* in_sizes, int n_in,
                              void* d_out, int out_size, void* d_ws, size_t ws_size,
                              hipStream_t stream) {
    const float* x      = (const float*)d_in[0];
    const float* conv_w = (const float*)d_in[1];
    const float* conv_b = (const float*)d_in[2];
    const float* bn1_g  = (const float*)d_in[3];
    const float* bn1_b  = (const float*)d_in[4];
    const float* bn1_m  = (const float*)d_in[5];
    const float* bn1_v  = (const float*)d_in[6];
    const float* W1     = (const float*)d_in[7];
    const float* b1     = (const float*)d_in[8];
    const float* bn2_g  = (const float*)d_in[9];
    const float* bn2_b  = (const float*)d_in[10];
    const float* bn2_m  = (const float*)d_in[11];
    const float* bn2_v  = (const float*)d_in[12];
    const float* W2     = (const float*)d_in[13];
    const float* b2     = (const float*)d_in[14];
    const float* bn3_g  = (const float*)d_in[15];
    const float* bn3_b  = (const float*)d_in[16];
    const float* bn3_m  = (const float*)d_in[17];
    const float* bn3_v  = (const float*)d_in[18];
    const float* cls_w  = (const float*)d_in[19];
    const float* cls_b  = (const float*)d_in[20];

    char* wsb = (char*)d_ws;
    ushort_t* pool0 = (ushort_t*)(wsb);                  // 15,360,000 B + 256 B pad
    ushort_t* pool1 = (ushort_t*)(wsb + 15360512);       // 15,360,000 B + 256 B pad
    ushort_t* Wc    = (ushort_t*)(wsb + 30721024);       //     58,368 B
    ushort_t* W1b   = (ushort_t*)(wsb + 30779392);       //  8,601,600 B
    float*    h2ws  = (float*)  (wsb + 39380992);        //    307,200 B

    prep_all<<<dim3(WC_BLKS + W1B_BLKS), 256, 0, stream>>>(conv_w, W1, Wc, W1b);

    conv_mfma<<<dim3(256, 2), 512, 0, stream>>>(
        x, Wc, conv_b, bn1_g, bn1_b, bn1_m, bn1_v, pool0, pool1);

    mlp_mfma<<<dim3(608), 256, 0, stream>>>(
        pool0, pool1, W1b, b1, bn2_g, bn2_b, bn2_m, bn2_v, W2, b2,
        bn3_g, bn3_b, bn3_m, bn3_v, h2ws);

    classifier_kernel<<<dim3(256), 64, 0, stream>>>(h2ws, cls_w, cls_b, (float*)d_out);
}

// Round 11
// 140.826 us; speedup vs baseline: 1.1141x; 1.0047x over previous
//
#include <hip/hip_runtime.h>

// ExplaiNN inference on MFMA (bf16 matrix cores, f32 accumulate). 4 dispatches:
// prep_wc:   conv_w -> Wc[kc][304][8] bf16 (tiny: 175KB moved, ~1us).
// conv_mfma: fused dispatch. Blocks [0,512): implicit-GEMM conv + BN1 + ReLU +
//            partial maxpool -> pool0/pool1 (r10 pipelined gt loop + raw-max epilogue,
//            unchanged). Blocks [512,2640): W1 -> W1b B-frag transform (r11: folded in —
//            W1b is only read by mlp, so its ~20MB of streaming traffic backfills CUs
//            as conv blocks drain instead of costing a serial prep dispatch).
// mlp_mfma:  per-group GEMM + BN2/ReLU + W2-dot + BN3/ReLU -> h2ws[g][b] (unchanged;
//            at its ~39MB memory floor). Combines pool0/pool1 via u16 max (values >= 0).
// classifier: h2 @ cls_w^T + cls_b -> out[256][2] f32 (unchanged).
// Ledger (r9/r10): harness fixed ~105-110us (1x 256MiB poison fill @44us + ~22 tiny
// reset dispatches + gaps); controllable: conv ~20.6, mlp ~6.2, prep ~3.5->1, cls ~2.5.

typedef unsigned short ushort_t;
typedef short short8 __attribute__((ext_vector_type(8)));
typedef float floatx4 __attribute__((ext_vector_type(4)));

constexpr float EPSf = 1e-5f;

__device__ __forceinline__ ushort_t f2bf(float f) {
    unsigned u = __float_as_uint(f);
    unsigned r = (u + 0x7FFFu + ((u >> 16) & 1u)) >> 16;   // round-to-nearest-even
    return (ushort_t)r;
}

__device__ __forceinline__ unsigned maxu16x2(unsigned a, unsigned b) {
    unsigned lo = (a & 0xffffu) > (b & 0xffffu) ? (a & 0xffffu) : (b & 0xffffu);
    unsigned hi = (a >> 16) > (b >> 16) ? (a >> 16) : (b >> 16);
    return lo | (hi << 16);
}

// opaque def of a uint4, component-wise (hipcc rejects tied 128-bit asm operands)
__device__ __forceinline__ void pin4(uint4& v) {
    asm volatile("" : "+v"(v.x), "+v"(v.y), "+v"(v.z), "+v"(v.w));
}

// ---------------- prep: Wc only ----------------
constexpr int WC_BLKS = 114;     // 29,184 ushorts = 12*304*8
__global__ __launch_bounds__(256) void prep_wc(
    const float* __restrict__ conv_w, ushort_t* __restrict__ Wc)
{
    int idx = blockIdx.x * 256 + threadIdx.x;        // exact: 114*256 = 29,184
    int j = idx & 7, g = (idx >> 3) % 304, kc = idx / (304 * 8);
    int k = kc * 8 + j, c = k / 24, tt = k - c * 24;
    float v = (g < 300 && tt < 19) ? conv_w[g * 76 + c * 19 + tt] : 0.f;
    Wc[idx] = f2bf(v);
}

// ---------------- Stage 1: conv (blocks 0-511) + W1b prep (blocks 512-2639) ----------------
// Conv: window q=0: p 0..51 (4 M-tiles), q=1: p 52..99 (3 M-tiles). X0 = x_pad origin.
// C[m=p][n=g] = sum_k A[m][k] B[k][n]; A[m][(c,t)] = x_pad[c][10(p)+d+t]; max over d-half.
constexpr int CONV_BLKS = 512;   // 256 b x 2 q
constexpr int W1B_BLKS  = 2128;  // 8 xcd * 38 g * 7 inner (3584 thr/g = 16kc*112h*2jj)
__global__ __launch_bounds__(512, 4) void conv_mfma(
    const float* __restrict__ x, const ushort_t* __restrict__ Wc,
    const float* __restrict__ conv_b, const float* __restrict__ g1, const float* __restrict__ be1,
    const float* __restrict__ m1, const float* __restrict__ v1,
    ushort_t* __restrict__ pool0, ushort_t* __restrict__ pool1,
    const float* __restrict__ W1, ushort_t* __restrict__ W1b)
{
    __shared__ ushort_t Wl[12 * 304 * 8];      // 58368 B, [kc][g][8]
    __shared__ ushort_t xl[16 * 552];          // 17664 B, [(phi*4+c)][552], phase-shifted copies
    __shared__ float A1s[304], B1s[304];       // total 78464 B -> 2 blocks/CU (16 waves/CU)

    const int tid = threadIdx.x;
    const int blk = blockIdx.x;

    if (blk >= CONV_BLKS) {
        // ---- W1b prep: W1 f32 -> W1b[g][kc][h][8] bf16 B-frag image ----
        int blk2 = blk - CONV_BLKS;
        int xcd = blk2 & 7, j = blk2 >> 3;           // j in [0, 266)
        int gl = j / 7, inner = j - gl * 7;
        int g = xcd * 38 + gl;
        if (g >= 300) return;
        int v = inner * 512 + tid;                   // 0..3583 exact (7*512)
        int jj = v & 1, r = v >> 1;
        int h = r % 112, kc = r / 112;
        int i0 = kc * 8 + jj * 4;
        ushort4 o = make_ushort4(0, 0, 0, 0);
        if (h < 100 && i0 <= 96) {
            float4 w = *(const float4*)&W1[(size_t)g * 10000 + h * 100 + i0];
            o = make_ushort4(f2bf(w.x), f2bf(w.y), f2bf(w.z), f2bf(w.w));
        }
        *(ushort4*)&W1b[((size_t)(g * 16 + kc) * 112 + h) * 8 + jj * 4] = o;
        return;
    }

    const int b = blk & 255, q = blk >> 8;
    const int X0 = q * 520;                     // x_pad coordinate of xl[.][0]

    // zero the 256B pad after EACH partial buffer (mlp overreads <=54B past last row;
    // ws is NaN-poisoned and NaN*0 = NaN through the zero-weight MFMA lanes).
    if (b == 0 && q == 0 && tid < 32) {
        ushort_t* bufp = (tid & 16) ? pool1 : pool0;
        uint4 z = {0, 0, 0, 0};
        *(uint4*)&bufp[7680000 + (tid & 15) * 8] = z;
    }

    // stage x (f32 global) -> 4 phase copies bf16 in LDS; copy phi elem i = x_pad[X0+i+phi]
    for (int u = tid; u < 16 * 276; u += 512) { // uint = 2 bf16
        int iu = u % 276, r = u / 276;
        int c = r & 3, phi = r >> 2;
        int gi = X0 + 2 * iu + phi - 9;         // x index of low element
        const float* xb = x + b * 4000 + c * 1000;
        float v0 = ((unsigned)gi < 1000u) ? xb[gi] : 0.f;
        float v1_ = ((unsigned)(gi + 1) < 1000u) ? xb[gi + 1] : 0.f;
        ((unsigned*)xl)[u] = (unsigned)f2bf(v0) | ((unsigned)f2bf(v1_) << 16);
    }
    {   // weights: linear 16B copy of prepped Wc (L2-resident, conflict-free)
        const uint4* wsrc = (const uint4*)Wc;
        uint4* wdst = (uint4*)Wl;
        for (int i = tid; i < 3648; i += 512) wdst[i] = wsrc[i];
    }
    for (int i = tid; i < 304; i += 512) {
        if (i < 300) {
            float A = g1[i] * rsqrtf(v1[i] + EPSf);
            A1s[i] = A;
            B1s[i] = (conv_b[i] - m1[i]) * A + be1[i];
        } else { A1s[i] = 0.f; B1s[i] = 0.f; }
    }
    __syncthreads();

    const int w = tid >> 6, lane = tid & 63;
    const int tile = w & 3, dh = w >> 2;        // dh=0: d 0..4, dh=1: d 5..9
    if (q == 1 && tile == 3) return;            // 3 tiles in window 1; no barriers after this
    const int p0 = q ? (52 + tile * 16) : (tile * 16);
    const int pmax = q ? 99 : 51;
    const int row = lane & 15, quad = lane >> 4;
    const int p_r = p0 + row;
    const int prc = (p_r < pmax) ? p_r : pmax;  // clamp keeps LDS reads in window (rows masked at store)
    ushort_t* __restrict__ dstbuf = dh ? pool1 : pool0;

    // A fragments for this wave's 5 d-shifts: 15 x uint4 = 60 VGPR.
    uint4 af[5][3];
#pragma unroll
    for (int s = 0; s < 3; ++s) {
        int k0 = s * 32 + quad * 8;
        int c = k0 / 24, t0 = k0 - c * 24;
        int base0 = 10 * prc + t0 - X0 + dh * 5; // local window coords, max 535 (q0) / 495 (q1)
#pragma unroll
        for (int dd = 0; dd < 5; ++dd) {
            int local = base0 + dd;
            int phi = local & 3, bi = local - phi;
            const ushort_t* p = &xl[(phi * 4 + c) * 552 + bi];  // 8B-aligned
            uint2 lo = *(const uint2*)p;
            uint2 hi = *(const uint2*)(p + 4);
            af[dd][s] = (uint4){lo.x, lo.y, hi.x, hi.y};
        }
    }
    // PIN: opaque volatile def per fragment — keep af register-resident across gt loop.
#pragma unroll
    for (int dd = 0; dd < 5; ++dd)
#pragma unroll
        for (int s = 0; s < 3; ++s)
            pin4(af[dd][s]);

    // --- pipelined gt loop: double-buffered B-frags, raw-max epilogue (r10) ---
    auto loadB = [&](short8* bf, int gt) {
#pragma unroll
        for (int s = 0; s < 3; ++s) {
            uint4 t4 = *(const uint4*)&Wl[(((s * 4 + quad) * 304) + gt * 16 + row) * 8];
            bf[s] = __builtin_bit_cast(short8, t4);
        }
    };
    auto compute = [&](const short8* bf, int gt) {
        floatx4 mx;
        {   // dd = 0 initializes the raw max
            floatx4 acc = {0.f, 0.f, 0.f, 0.f};
#pragma unroll
            for (int s = 0; s < 3; ++s)
                acc = __builtin_amdgcn_mfma_f32_16x16x32_bf16(
                    __builtin_bit_cast(short8, af[0][s]), bf[s], acc, 0, 0, 0);
            mx = acc;
        }
#pragma unroll
        for (int dd = 1; dd < 5; ++dd) {
            floatx4 acc = {0.f, 0.f, 0.f, 0.f};
#pragma unroll
            for (int s = 0; s < 3; ++s)
                acc = __builtin_amdgcn_mfma_f32_16x16x32_bf16(
                    __builtin_bit_cast(short8, af[dd][s]), bf[s], acc, 0, 0, 0);
#pragma unroll
            for (int r = 0; r < 4; ++r)
                mx[r] = fmaxf(mx[r], acc[r]);
        }
        const int g = gt * 16 + row;            // C col = lane&15
        const int pr0 = p0 + quad * 4;          // C rows = quad*4 + r
        if (g < 300 && pr0 + 3 <= pmax) {
            const float a1v = A1s[g], b1v = B1s[g];   // BN AFTER max (A1 > 0: monotone)
            ushort4 o;
            o.x = f2bf(fmaxf(fmaf(mx[0], a1v, b1v), 0.f));
            o.y = f2bf(fmaxf(fmaf(mx[1], a1v, b1v), 0.f));
            o.z = f2bf(fmaxf(fmaf(mx[2], a1v, b1v), 0.f));
            o.w = f2bf(fmaxf(fmaf(mx[3], a1v, b1v), 0.f));
            *(ushort4*)&dstbuf[((size_t)b * 300 + g) * 100 + pr0] = o;
        }
    };

    short8 bf0[3], bf1[3];
    loadB(bf0, 0);
    for (int gt = 0; gt < 19; gt += 2) {
        if (gt + 1 < 19) loadB(bf1, gt + 1);    // prefetch under gt's MFMAs
        compute(bf0, gt);
        if (gt + 2 < 19) loadB(bf0, gt + 2);    // prefetch under gt+1's MFMAs
        if (gt + 1 < 19) compute(bf1, gt + 1);
    }
}

// ---------------- Stage 2: grouped MLP via MFMA (unchanged) ----------------
// grid 608: blk&7 = XCD slice, 38 g each, 2 b-halves per g on the same slice.
__global__ __launch_bounds__(256, 2) void mlp_mfma(
    const ushort_t* __restrict__ pool0, const ushort_t* __restrict__ pool1,
    const ushort_t* __restrict__ W1b,
    const float* __restrict__ b1, const float* __restrict__ g2, const float* __restrict__ be2,
    const float* __restrict__ m2, const float* __restrict__ v2,
    const float* __restrict__ W2, const float* __restrict__ b2,
    const float* __restrict__ g3, const float* __restrict__ be3,
    const float* __restrict__ m3, const float* __restrict__ v3,
    float* __restrict__ h2ws)
{
    __shared__ ushort_t W1l[16 * 112 * 8];     // 28672 B, [kc][h][8]
    __shared__ ushort_t pl[128 * 128];         // 32768 B, [bl][chunk^(bl&7)][8]
    __shared__ float A2s[112], C2s[112], w2sl[112];
    __shared__ float sA3, sC3;

    const int tid = threadIdx.x;
    const int blk = blockIdx.x;
    const int xcd = blk & 7, j = blk >> 3;
    const int g = xcd * 38 + (j >> 1);
    if (g >= 300) return;
    const int b0 = (j & 1) * 128;

    {   // pure linear copy of prepped B-frag image (conflict-free)
        const uint4* src = (const uint4*)(W1b + (size_t)g * 14336);
        uint4* dst = (uint4*)W1l;
        for (int i = tid; i < 1792; i += 256) dst[i] = src[i];
    }
    for (int qq = tid; qq < 128 * 16; qq += 256) {
        int bl = qq >> 4, kc = qq & 15;
        size_t off = ((size_t)(b0 + bl) * 300 + g) * 100 + kc * 8;
        const ushort_t* sA = pool0 + off;       // rows 200B apart: 8B-aligned
        const ushort_t* sB = pool1 + off;       // i>=100 spills into next row / zero pad (finite)
        uint2 loA = *(const uint2*)sA, hiA = *(const uint2*)(sA + 4);
        uint2 loB = *(const uint2*)sB, hiB = *(const uint2*)(sB + 4);
        uint4 m;                                // combine d-halves: u16 max (post-ReLU bf16 >= 0)
        m.x = maxu16x2(loA.x, loB.x);
        m.y = maxu16x2(loA.y, loB.y);
        m.z = maxu16x2(hiA.x, hiB.x);
        m.w = maxu16x2(hiA.y, hiB.y);
        int swz = kc ^ (bl & 7);
        *(uint4*)&pl[((bl * 16) + swz) * 8] = m;
    }
    if (tid < 112) {
        float a2 = 0.f, c2 = 0.f, w2v = 0.f;
        if (tid < 100) {
            int qq = g * 100 + tid;
            a2 = g2[qq] * rsqrtf(v2[qq] + EPSf);
            c2 = (b1[qq] - m2[qq]) * a2 + be2[qq];
            w2v = W2[qq];
        }
        A2s[tid] = a2; C2s[tid] = c2; w2sl[tid] = w2v;
    }
    if (tid == 0) {
        float a3 = g3[g] * rsqrtf(v3[g] + EPSf);
        sA3 = a3; sC3 = (b2[g] - m3[g]) * a3 + be3[g];
    }
    __syncthreads();

    const int w = tid >> 6, lane = tid & 63;
    const int col = lane & 15, quad = lane >> 4;

    uint4 bfr[7][4];                           // all B-frags cached (112 VGPR), pinned below
#pragma unroll
    for (int nt = 0; nt < 7; ++nt)
#pragma unroll
        for (int s = 0; s < 4; ++s)
            bfr[nt][s] = *(const uint4*)&W1l[(((s * 4 + quad) * 112) + nt * 16 + col) * 8];
#pragma unroll
    for (int nt = 0; nt < 7; ++nt)
#pragma unroll
        for (int s = 0; s < 4; ++s)
            pin4(bfr[nt][s]);

#pragma unroll
    for (int mi = 0; mi < 2; ++mi) {
        const int mt = w * 2 + mi;
        const int bl = mt * 16 + col;          // A row
        uint4 afr[4];
#pragma unroll
        for (int s = 0; s < 4; ++s) {
            int kc = s * 4 + quad;
            afr[s] = *(const uint4*)&pl[((bl * 16) + (kc ^ (bl & 7))) * 8];
        }
        float run0 = 0.f, run1 = 0.f, run2 = 0.f, run3 = 0.f;
#pragma unroll
        for (int nt = 0; nt < 7; ++nt) {
            floatx4 acc = {0.f, 0.f, 0.f, 0.f};
#pragma unroll
            for (int s = 0; s < 4; ++s)
                acc = __builtin_amdgcn_mfma_f32_16x16x32_bf16(
                    __builtin_bit_cast(short8, afr[s]), __builtin_bit_cast(short8, bfr[nt][s]), acc, 0, 0, 0);
            const float a2v = A2s[nt * 16 + col], c2v = C2s[nt * 16 + col], w2v = w2sl[nt * 16 + col];
            run0 += fmaxf(fmaf(acc[0], a2v, c2v), 0.f) * w2v;
            run1 += fmaxf(fmaf(acc[1], a2v, c2v), 0.f) * w2v;
            run2 += fmaxf(fmaf(acc[2], a2v, c2v), 0.f) * w2v;
            run3 += fmaxf(fmaf(acc[3], a2v, c2v), 0.f) * w2v;
        }
#pragma unroll
        for (int m = 1; m <= 8; m <<= 1) {     // sum over the 16 h-cols
            run0 += __shfl_xor(run0, m, 64);
            run1 += __shfl_xor(run1, m, 64);
            run2 += __shfl_xor(run2, m, 64);
            run3 += __shfl_xor(run3, m, 64);
        }
        if (col == 0) {
            float4 o;
            o.x = fmaxf(fmaf(run0, sA3, sC3), 0.f);
            o.y = fmaxf(fmaf(run1, sA3, sC3), 0.f);
            o.z = fmaxf(fmaf(run2, sA3, sC3), 0.f);
            o.w = fmaxf(fmaf(run3, sA3, sC3), 0.f);
            *(float4*)&h2ws[g * 256 + b0 + mt * 16 + quad * 4] = o;
        }
    }
}

// ---------------- Stage 3: classifier ----------------
__global__ __launch_bounds__(64) void classifier_kernel(
    const float* __restrict__ h2ws, const float* __restrict__ cls_w,
    const float* __restrict__ cls_b, float* __restrict__ out) {
    const int b = blockIdx.x, t = threadIdx.x;
    float a0 = 0.f, a1 = 0.f;
    for (int gg = t; gg < 300; gg += 64) {
        float v = h2ws[gg * 256 + b];
        a0 = fmaf(v, cls_w[gg], a0);
        a1 = fmaf(v, cls_w[300 + gg], a1);
    }
#pragma unroll
    for (int off = 32; off; off >>= 1) {
        a0 += __shfl_down(a0, off);
        a1 += __shfl_down(a1, off);
    }
    if (t == 0) {
        out[b * 2 + 0] = a0 + cls_b[0];
        out[b * 2 + 1] = a1 + cls_b[1];
    }
}

extern "C" void kernel_launch(void* const* d_in, const int* in_sizes, int n_in,
                              void* d_out, int out_size, void* d_ws, size_t ws_size,
                              hipStream_t stream) {
    const float* x      = (const float*)d_in[0];
    const float* conv_w = (const float*)d_in[1];
    const float* conv_b = (const float*)d_in[2];
    const float* bn1_g  = (const float*)d_in[3];
    const float* bn1_b  = (const float*)d_in[4];
    const float* bn1_m  = (const float*)d_in[5];
    const float* bn1_v  = (const float*)d_in[6];
    const float* W1     = (const float*)d_in[7];
    const float* b1     = (const float*)d_in[8];
    const float* bn2_g  = (const float*)d_in[9];
    const float* bn2_b  = (const float*)d_in[10];
    const float* bn2_m  = (const float*)d_in[11];
    const float* bn2_v  = (const float*)d_in[12];
    const float* W2     = (const float*)d_in[13];
    const float* b2     = (const float*)d_in[14];
    const float* bn3_g  = (const float*)d_in[15];
    const float* bn3_b  = (const float*)d_in[16];
    const float* bn3_m  = (const float*)d_in[17];
    const float* bn3_v  = (const float*)d_in[18];
    const float* cls_w  = (const float*)d_in[19];
    const float* cls_b  = (const float*)d_in[20];

    char* wsb = (char*)d_ws;
    ushort_t* pool0 = (ushort_t*)(wsb);                  // 15,360,000 B + 256 B pad
    ushort_t* pool1 = (ushort_t*)(wsb + 15360512);       // 15,360,000 B + 256 B pad
    ushort_t* Wc    = (ushort_t*)(wsb + 30721024);       //     58,368 B
    ushort_t* W1b   = (ushort_t*)(wsb + 30779392);       //  8,601,600 B
    float*    h2ws  = (float*)  (wsb + 39380992);        //    307,200 B

    prep_wc<<<dim3(WC_BLKS), 256, 0, stream>>>(conv_w, Wc);

    conv_mfma<<<dim3(CONV_BLKS + W1B_BLKS), 512, 0, stream>>>(
        x, Wc, conv_b, bn1_g, bn1_b, bn1_m, bn1_v, pool0, pool1, W1, W1b);

    mlp_mfma<<<dim3(608), 256, 0, stream>>>(
        pool0, pool1, W1b, b1, bn2_g, bn2_b, bn2_m, bn2_v, W2, b2,
        bn3_g, bn3_b, bn3_m, bn3_v, h2ws);

    classifier_kernel<<<dim3(256), 64, 0, stream>>>(h2ws, cls_w, cls_b, (float*)d_out);
}